// Round 11
// baseline (224.484 us; speedup 1.0000x reference)
//
#include <hip/hip_runtime.h>
#include <hip/hip_bf16.h>

// GravNetConv: N=16384, C_IN=128, S=4, P=32, K=16, C_OUT=128.
// Mask path: [k1] proj (fp64 s) -> [k2t] threshold via radix-ladder histogram ->
// [k2b] full N^2 Gram-form scan, M=8 queries/thread, mask stored as 4 dword PLANES
// (coalesced dword stores along q) -> [k3_sel4] 32 q/block, lane=query coalesced
// plane reads, ktop2-anchored class histogram, rank-based winners, remapped
// coalesced aggregation -> [k4a/k4_out2] output GEMM.
// Fallback path (ws_size < 41MB): round-2 kernels.

#define NPTS 16384
#define CIN  128
#define SD   4
#define PD   32
#define KNN  16
#define COUT 128
#define FLTMAX 3.4028234663852886e+38f
#define NBIN 33
#define QB3  32     // k3 queries per block
#define QCAP 512    // per-query candidate cap
#define MCAP 64     // per-query qualifier cap (slow exact fallback if exceeded)

typedef float v2f __attribute__((ext_vector_type(2)));
typedef unsigned int uint;
typedef unsigned long long u64;

// ---- shared offsets (both paths) ----
#define WS_S4     0            // N * float4 = 256 KB
#define WS_H      0x40000      // N * 32 f32 = 2 MB
// ---- mask-path offsets ----
#define WS_AGG_M  0x280000     // [N][64] f32 = 4 MB
#define WS_WT_M   0x680000     // [192][128] f32 = 96 KB
#define WS_T2     0x6A0000     // N f32 = 64 KB
#define WS_MASK   0x700000     // 4 planes x 128c x N dwords = 32 MB
#define WS_NEED_M 0x2700000    // 40.9 MB
#define PLANE     ((size_t)128*NPTS)   // dwords per plane
// ---- fallback offsets ----
#define WS_CJ_F   0x400000
#define WS_AGG_F  0xC00000
#define WS_WT_F   0x1000000
#define JS   16
#define TJF  (NPTS/JS)

__device__ __forceinline__ float d2f(const float4 a, const float4 b) {
  v2f d0 = {a.x - b.x, a.y - b.y};
  v2f d1 = {a.z - b.z, a.w - b.w};
  v2f pr = d0*d0 + d1*d1;
  return pr.x + pr.y;
}

// ---------------- Kernel 1: s (fp64 accumulate) and h projections ----------------
__global__ __launch_bounds__(256) void k1_proj(
    const float* __restrict__ x, const float* __restrict__ Ws, const float* __restrict__ bs,
    const float* __restrict__ Wh, const float* __restrict__ bh,
    float4* __restrict__ s4, float* __restrict__ h) {
  __shared__ float  lw[36*128];
  __shared__ float  lx[64*132];
  __shared__ double rs[3*64*5];
  __shared__ float  rh[3*64*33];
  const int t = threadIdx.x;
  const int row0 = blockIdx.x * 64;
  for (int i2 = t; i2 < 36*128; i2 += 256)
    lw[i2] = (i2 < 512) ? Ws[i2] : Wh[i2 - 512];
#pragma unroll
  for (int g = 0; g < 8; ++g) {
    int fi = g*256 + t;
    int r = fi >> 5, c4 = fi & 31;
    *(float4*)&lx[r*132 + c4*4] = *(const float4*)&x[(size_t)(row0 + r)*CIN + c4*4];
  }
  __syncthreads();
  const int kq = t >> 6;
  const int r  = t & 63;
  const int kb = kq * 32;
  double sacc[4] = {0.0, 0.0, 0.0, 0.0};
  float  hacc[32];
#pragma unroll
  for (int p = 0; p < 32; ++p) hacc[p] = 0.f;
#pragma unroll
  for (int k4 = 0; k4 < 8; ++k4) {
    float4 xv = *(const float4*)&lx[r*132 + kb + k4*4];
    int kg = kb + k4*4;
#pragma unroll
    for (int p = 0; p < 4; ++p) {
      float4 wv = *(const float4*)&lw[p*128 + kg];
      sacc[p] = fma((double)xv.x, (double)wv.x, sacc[p]);
      sacc[p] = fma((double)xv.y, (double)wv.y, sacc[p]);
      sacc[p] = fma((double)xv.z, (double)wv.z, sacc[p]);
      sacc[p] = fma((double)xv.w, (double)wv.w, sacc[p]);
    }
#pragma unroll
    for (int p = 0; p < 32; ++p) {
      float4 wv = *(const float4*)&lw[(4+p)*128 + kg];
      hacc[p] = fmaf(xv.x, wv.x, fmaf(xv.y, wv.y, fmaf(xv.z, wv.z, fmaf(xv.w, wv.w, hacc[p]))));
    }
  }
  if (kq > 0) {
    const int bq = kq - 1;
#pragma unroll
    for (int d = 0; d < 4; ++d) rs[(bq*64 + r)*5 + d] = sacc[d];
#pragma unroll
    for (int p = 0; p < 32; ++p) rh[(bq*64 + r)*33 + p] = hacc[p];
  }
  __syncthreads();
  if (kq == 0) {
    const int row = row0 + r;
    float so[4];
#pragma unroll
    for (int d = 0; d < 4; ++d) {
      double sd = sacc[d] + rs[(0*64 + r)*5 + d] + rs[(1*64 + r)*5 + d]
                + rs[(2*64 + r)*5 + d] + (double)bs[d];
      so[d] = (float)sd;
    }
    s4[row] = make_float4(so[0], so[1], so[2], so[3]);
#pragma unroll
    for (int p4 = 0; p4 < 8; ++p4) {
      float o[4];
#pragma unroll
      for (int c = 0; c < 4; ++c) {
        int p = p4*4 + c;
        o[c] = hacc[p] + rh[(0*64 + r)*33 + p] + rh[(1*64 + r)*33 + p]
             + rh[(2*64 + r)*33 + p] + bh[p];
      }
      *(float4*)&h[(size_t)row*PD + p4*4] = make_float4(o[0], o[1], o[2], o[3]);
    }
  }
}

// ---------------- Kernel 2t: per-query threshold via radix-ladder histogram ----------------
__global__ __launch_bounds__(256) void k2t_thresh(
    const float4* __restrict__ s4, float* __restrict__ t2) {
  __shared__ float4 tile[2064];
  __shared__ uint   lhist[256*NBIN];
  const int t = threadIdx.x;
#pragma unroll
  for (int g = 0; g < 8; ++g) {
    int j = g*256 + t;
    tile[j + (j >> 7)] = s4[j];
  }
#pragma unroll
  for (int b = 0; b < NBIN; ++b) lhist[t*NBIN + b] = 0u;
  const int ql = t >> 4, tq = t & 15;
  const int q  = blockIdx.x*16 + ql;
  const float4 sq = s4[q];
  __syncthreads();
  float tau = d2f(sq, tile[tq*129]);
#pragma unroll
  for (int m = 1; m < 16; m <<= 1) tau = fmaxf(tau, __shfl_xor(tau, m, 16));
  const int ktop = (int)(__float_as_uint(tau) >> 21);
  const int hb = t*NBIN;
#pragma unroll 4
  for (int u = 0; u < 128; ++u) {
    float4 p = tile[tq*129 + u];
    float e = d2f(sq, p);
    int key = (int)(__float_as_uint(e) >> 21);
    int rel = ktop - key;
    rel = rel < 0 ? 0 : (rel > 32 ? 32 : rel);
    atomicAdd(&lhist[hb + rel], 1u);
  }
  __syncthreads();
  uint c0 = 0, c1 = 0;
  const int qb = ql*16;
  for (int u = 0; u < 16; ++u) {
    c0 += lhist[(qb + u)*NBIN + tq*2];
    c1 += (tq*2 + 1 < NBIN) ? lhist[(qb + u)*NBIN + tq*2 + 1] : 0u;
  }
  int S = (int)(c0 + c1);
#pragma unroll
  for (int d = 1; d < 16; d <<= 1) {
    int v = __shfl_down(S, d, 16);
    S += (tq + d < 16) ? v : 0;
  }
  int g = -1;
  if (S >= KNN) g = 2*tq;
  if (S - (int)c0 >= KNN) g = 2*tq + 1;
#pragma unroll
  for (int m = 1; m < 16; m <<= 1) g = max(g, __shfl_xor(g, m, 16));
  if (tq == 0) {
    uint K = (uint)(ktop - g);
    t2[q] = __uint_as_float((K << 21) | 0x1FFFFFu);
  }
}

// ---------------- Kernel 2b: full scan -> 4 mask planes, M=8, coalesced dword stores ------
// Gram test: d2 <= t2+eps  <=>  si.sj - bj >= ui  (4-fma chain + cmp + addc per pair).
__global__ __launch_bounds__(256) void k2b_mask(
    const float4* __restrict__ s4, const float* __restrict__ t2, uint* __restrict__ mp) {
  __shared__ float4 tile4[128];
  __shared__ float  tileb[128];
  const int t  = threadIdx.x;
  const int c  = blockIdx.x >> 3;   // 128 chunks
  const int ig = blockIdx.x & 7;    // 8 query groups of 2048
  if (t < 128) {
    float4 p = s4[c*128 + t];
    tile4[t] = p;
    tileb[t] = 0.5f*(p.x*p.x + p.y*p.y + p.z*p.z + p.w*p.w);
  }
  const int q0 = ig*2048 + t;
  float4 sq[8]; float ui[8];
#pragma unroll
  for (int m = 0; m < 8; ++m) {
    int q = q0 + m*256;
    float4 s = s4[q];
    sq[m] = s;
    float n2 = s.x*s.x + s.y*s.y + s.z*s.z + s.w*s.w;
    ui[m] = 0.5f*(n2 - t2[q]) - 4e-6f;
  }
  __syncthreads();
#pragma unroll 1
  for (int w = 0; w < 4; ++w) {
    uint mk[8] = {0u,0u,0u,0u,0u,0u,0u,0u};
#pragma unroll
    for (int bit = 31; bit >= 0; --bit) {
      float4 p = tile4[w*32 + bit];
      float nb = tileb[w*32 + bit];
#pragma unroll
      for (int m = 0; m < 8; ++m) {
        float a = fmaf(sq[m].x, p.x, fmaf(sq[m].y, p.y,
                  fmaf(sq[m].z, p.z, fmaf(sq[m].w, p.w, -nb))));
        mk[m] = mk[m] + mk[m] + (a >= ui[m] ? 1u : 0u);
      }
    }
    uint* pl = mp + (size_t)w*PLANE + (size_t)c*NPTS;
#pragma unroll
    for (int m = 0; m < 8; ++m) pl[q0 + m*256] = mk[m];   // coalesced dwords along q
  }
}

// ---------------- Kernel 3: coalesced plane read + rank selection + aggregation -----------
// block = 32 queries (QL = t&31) x 8 teams (TM = t>>5); team TM covers chunks [TM*16,TM*16+16).
// Class window anchored at ktop2 = class(t2): rel = clamp(ktop2-cls, 0, 31);
// qualifier predicate rel >= rstar is count-consistent by construction.
__global__ __launch_bounds__(256) void k3_sel4(
    const float4* __restrict__ s4, const float4* __restrict__ h4,
    const float* __restrict__ t2, const uint* __restrict__ mp,
    float* __restrict__ agg) {
  __shared__ unsigned short cand[QCAP*QB3];   // [u*32+QL] 32 KB
  __shared__ u64  qual[MCAP*QB3];             // [p*32+QL] 16 KB
  __shared__ u64  win[KNN*QB3];               // [r*32+QL] 4 KB
  __shared__ uint hist[32*QB3];               // [rel*32+QL] 4 KB
  __shared__ uint cnts[QB3];
  __shared__ uint mc[QB3];
  __shared__ uint rst[QB3];
  const int t  = threadIdx.x;
  const int QL = t & 31, TM = t >> 5;
  const int q0 = blockIdx.x*QB3;
  const int q  = q0 + QL;
  if (TM == 0) { cnts[QL] = 0u; mc[QL] = 0u; }
#pragma unroll
  for (int r = 0; r < 4; ++r) hist[(TM*4 + r)*32 + QL] = 0u;
  if (TM < 2) win[(TM*8 + (QL & 7))*32 + (QL >> 3) + (TM & 0)*0] = 0ull;  // partial; full init below
#pragma unroll
  for (int r = TM; r < KNN; r += 8) win[r*32 + QL] = 0ull;
  const float4 sq = s4[q];
  const uint ktop2 = __float_as_uint(t2[q]) >> 21;
  __syncthreads();
  // ---- phase A: extract candidates; mask reads coalesced along q ----
  for (int ci = 0; ci < 16; ++ci) {
    const int c = TM*16 + ci;
    const uint* base = mp + (size_t)c*NPTS + q;
    uint wv0 = base[0*PLANE], wv1 = base[1*PLANE], wv2 = base[2*PLANE], wv3 = base[3*PLANE];
    int pc = __popc(wv0) + __popc(wv1) + __popc(wv2) + __popc(wv3);
    if (pc > 0) {
      int base_i = (int)atomicAdd(&cnts[QL], (uint)pc);
      uint wvs[4] = {wv0, wv1, wv2, wv3};
#pragma unroll
      for (int w = 0; w < 4; ++w) {
        uint bits = wvs[w];
        const int jb = c*128 + w*32;
        while (bits) {
          int b = __builtin_ctz(bits); bits &= bits - 1;
          if (base_i < QCAP) cand[base_i*32 + QL] = (unsigned short)(jb + b);
          ++base_i;
        }
      }
    }
  }
  __syncthreads();
  const int cnt = min((int)cnts[QL], QCAP);
  // ---- phase B: class histogram (ktop2-anchored, signed clamp) ----
  for (int u = TM; u < cnt; u += 8) {
    int j = cand[u*32 + QL];
    float e = d2f(sq, s4[j]);
    int rel = (int)ktop2 - (int)(__float_as_uint(e) >> 21);
    rel = rel < 0 ? 0 : (rel > 31 ? 31 : rel);
    atomicAdd(&hist[rel*32 + QL], 1u);
  }
  __syncthreads();
  // ---- phase C: rstar = largest r with suffix-cum >= need (serial, team 0) ----
  if (TM == 0) {
    const uint need = (uint)(cnt < KNN ? cnt : KNN);
    uint acc = 0; uint rs_ = 0;
    for (int r = 31; r >= 0; --r) {
      acc += hist[r*32 + QL];
      if (acc >= need) { rs_ = (uint)r; break; }
    }
    rst[QL] = rs_;
  }
  __syncthreads();
  const uint rstar = rst[QL];
  // ---- phase D: compact qualifier keys ----
  for (int u = TM; u < cnt; u += 8) {
    int j = cand[u*32 + QL];
    float e = d2f(sq, s4[j]);
    uint db = __float_as_uint(e);
    int rel = (int)ktop2 - (int)(db >> 21);
    rel = rel < 0 ? 0 : (rel > 31 ? 31 : rel);
    if ((uint)rel >= rstar) {
      uint pos = atomicAdd(&mc[QL], 1u);
      if (pos < MCAP) qual[pos*32 + QL] = ((u64)db << 14) | (uint)j;
    }
  }
  __syncthreads();
  // ---- phase E: exact rank among qualifiers -> winners ----
  const int mcnt = (int)mc[QL];
  if (mcnt <= MCAP) {
    for (int w = TM; w < mcnt; w += 8) {
      u64 key = qual[w*32 + QL];
      int rank = 0;
      for (int v = 0; v < mcnt; ++v) rank += (qual[v*32 + QL] < key) ? 1 : 0;
      if (rank < KNN) win[rank*32 + QL] = key;
    }
  } else {
    // rare overflow: exact rank against full candidate list (recomputed keys)
    for (int u = TM; u < cnt; u += 8) {
      int j = cand[u*32 + QL];
      float e = d2f(sq, s4[j]);
      uint db = __float_as_uint(e);
      int rel = (int)ktop2 - (int)(db >> 21);
      rel = rel < 0 ? 0 : (rel > 31 ? 31 : rel);
      if ((uint)rel < rstar) continue;
      u64 key = ((u64)db << 14) | (uint)j;
      int rank = 0;
      for (int v = 0; v < cnt; ++v) {
        int jv = cand[v*32 + QL];
        float ev = d2f(sq, s4[jv]);
        u64 kv = ((u64)__float_as_uint(ev) << 14) | (uint)jv;
        rank += (kv < key) ? 1 : 0;
      }
      if (rank < KNN) win[rank*32 + QL] = key;
    }
  }
  __syncthreads();
  // ---- phase F: aggregation, remapped for coalesced writes ----
  const int QL2 = t >> 3, TM2 = t & 7;   // 32 queries x 8 comp-groups of 4
  const int q2  = q0 + QL2;
  float s0 = 0.f, s1 = 0.f, s2 = 0.f, s3 = 0.f;
  float m0 = -FLTMAX, m1 = -FLTMAX, m2 = -FLTMAX, m3 = -FLTMAX;
#pragma unroll 1
  for (int r = 0; r < KNN; ++r) {
    u64 key = win[r*32 + QL2];
    float d2 = __uint_as_float((uint)(key >> 14));
    int j = (int)(key & 16383u);
    float w = __expf(-10.f * d2);
    float4 hv = h4[(size_t)j*8 + TM2];
    float a0 = hv.x*w, a1 = hv.y*w, a2 = hv.z*w, a3 = hv.w*w;
    s0 += a0; s1 += a1; s2 += a2; s3 += a3;
    m0 = fmaxf(m0, a0); m1 = fmaxf(m1, a1); m2 = fmaxf(m2, a2); m3 = fmaxf(m3, a3);
  }
  *(float4*)&agg[(size_t)q2*64 + TM2*4] =
      make_float4(s0*0.0625f, s1*0.0625f, s2*0.0625f, s3*0.0625f);
  *(float4*)&agg[(size_t)q2*64 + 32 + TM2*4] = make_float4(m0, m1, m2, m3);
}

// ================= Fallback path (round-2, proven) =================
__global__ __launch_bounds__(256) void k2_knn_fb(
    const float4* __restrict__ s4, unsigned short* __restrict__ cand_j) {
  __shared__ float4 tile[TJF];
  __shared__ int    lbuf[256*33];
  const int t  = threadIdx.x;
  const int ib = blockIdx.x & 31;
  const int jc = blockIdx.x >> 5;
  const int jbase = jc * TJF;
#pragma unroll
  for (int g = 0; g < 4; ++g) tile[g*256 + t] = s4[jbase + g*256 + t];
  const int ia = ib*256 + t;
  const int ic = ia + 8192;
  const float4 sa = s4[ia];
  const float4 sc = s4[ic];
  __syncthreads();
  float va[KNN], vb[KNN]; int ja[KNN], jb[KNN];
#pragma unroll
  for (int q = 0; q < KNN; ++q) { va[q] = FLTMAX; ja[q] = 0; vb[q] = FLTMAX; jb[q] = 0; }
  float cma = FLTMAX, cmb = FLTMAX;
  int cpa = 0, cpb = 0, ca = 0, cb = 0;
  auto insertA = [&](float e, int jj) {
#pragma unroll
    for (int q = 0; q < KNN; ++q) if (q == cpa) { va[q] = e; ja[q] = jj; }
    cma = va[0]; cpa = 0;
#pragma unroll
    for (int q = 1; q < KNN; ++q) { if (va[q] > cma) { cma = va[q]; cpa = q; } }
  };
  auto insertB = [&](float e, int jj) {
#pragma unroll
    for (int q = 0; q < KNN; ++q) if (q == cpb) { vb[q] = e; jb[q] = jj; }
    cmb = vb[0]; cpb = 0;
#pragma unroll
    for (int q = 1; q < KNN; ++q) { if (vb[q] > cmb) { cmb = vb[q]; cpb = q; } }
  };
  auto compactA = [&]() {
    for (int u = 0; u < ca; ++u) {
      int jj = lbuf[t*33 + u];
      float e = d2f(sa, tile[jj]);
      if (e < cma) insertA(e, jj);
    }
    ca = 0;
  };
  auto compactB = [&]() {
    for (int u = 0; u < cb; ++u) {
      int jj = lbuf[t*33 + 16 + u];
      float e = d2f(sc, tile[jj]);
      if (e < cmb) insertB(e, jj);
    }
    cb = 0;
  };
  for (int ob = 0; ob < TJF/8; ++ob) {
#pragma unroll
    for (int u = 0; u < 8; ++u) {
      int jj = ob*8 + u;
      float4 p = tile[jj];
      float ea = d2f(sa, p);
      float eb = d2f(sc, p);
      if (ea < cma) { lbuf[t*33 + ca] = jj; ++ca; }
      if (eb < cmb) { lbuf[t*33 + 16 + cb] = jj; ++cb; }
    }
    if (__any(ca > 8)) compactA();
    if (__any(cb > 8)) compactB();
  }
  compactA(); compactB();
#pragma unroll
  for (int q = 0; q < KNN; ++q) {
    int c = jc*KNN + q;
    cand_j[(size_t)c*NPTS + ia] = (unsigned short)(ja[q] + jbase);
    cand_j[(size_t)c*NPTS + ic] = (unsigned short)(jb[q] + jbase);
  }
}

__global__ __launch_bounds__(256) void k3_merge_fb(
    const float4* __restrict__ s4, const float4* __restrict__ h4,
    const unsigned short* __restrict__ cand_j, float* __restrict__ agg) {
  __shared__ float le[64*67];
  __shared__ int   lj[64*67];
  const int t  = threadIdx.x;
  const int il = t & 63, tq = t >> 6;
  const int i  = blockIdx.x*64 + il;
  const float4 si = s4[i];
  float val[KNN]; int vid[KNN];
#pragma unroll
  for (int q = 0; q < KNN; ++q) { val[q] = FLTMAX; vid[q] = 0; }
  float cmax = FLTMAX; int cpos = 0;
  for (int u = 0; u < 64; ++u) {
    int c = tq*64 + u;
    int j = cand_j[(size_t)c*NPTS + i];
    float e = d2f(si, s4[j]);
    if (e < cmax) {
#pragma unroll
      for (int q = 0; q < KNN; ++q) if (q == cpos) { val[q] = e; vid[q] = j; }
      cmax = val[0]; cpos = 0;
#pragma unroll
      for (int q = 1; q < KNN; ++q) { if (val[q] > cmax) { cmax = val[q]; cpos = q; } }
    }
  }
#pragma unroll
  for (int q = 0; q < KNN; ++q) {
    le[il*67 + tq*16 + q] = val[q];
    lj[il*67 + tq*16 + q] = vid[q];
  }
  __syncthreads();
  if (t < 64) {
    float mv[KNN]; int mj[KNN];
#pragma unroll
    for (int q = 0; q < KNN; ++q) { mv[q] = FLTMAX; mj[q] = 0; }
    float cm2 = FLTMAX; int cp2 = 0;
    for (int u = 0; u < 64; ++u) {
      float e = le[t*67 + u];
      int   j = lj[t*67 + u];
      if (e < cm2) {
#pragma unroll
        for (int q = 0; q < KNN; ++q) if (q == cp2) { mv[q] = e; mj[q] = j; }
        cm2 = mv[0]; cp2 = 0;
#pragma unroll
        for (int q = 1; q < KNN; ++q) { if (mv[q] > cm2) { cm2 = mv[q]; cp2 = q; } }
      }
    }
#pragma unroll
    for (int q = 0; q < KNN; ++q) {
      le[t*67 + q] = __expf(-10.f * mv[q]);
      lj[t*67 + q] = mj[q];
    }
  }
  __syncthreads();
  float ms[8], mm[8];
#pragma unroll
  for (int p = 0; p < 8; ++p) { ms[p] = 0.f; mm[p] = -FLTMAX; }
#pragma unroll 1
  for (int q = 0; q < KNN; ++q) {
    float w = le[il*67 + q];
    int   j = lj[il*67 + q];
    float4 a = h4[(size_t)j*8 + tq*2];
    float4 b = h4[(size_t)j*8 + tq*2 + 1];
    float m0 = a.x*w, m1 = a.y*w, m2 = a.z*w, m3 = a.w*w;
    float m4 = b.x*w, m5 = b.y*w, m6 = b.z*w, m7 = b.w*w;
    ms[0] += m0; mm[0] = fmaxf(mm[0], m0);
    ms[1] += m1; mm[1] = fmaxf(mm[1], m1);
    ms[2] += m2; mm[2] = fmaxf(mm[2], m2);
    ms[3] += m3; mm[3] = fmaxf(mm[3], m3);
    ms[4] += m4; mm[4] = fmaxf(mm[4], m4);
    ms[5] += m5; mm[5] = fmaxf(mm[5], m5);
    ms[6] += m6; mm[6] = fmaxf(mm[6], m6);
    ms[7] += m7; mm[7] = fmaxf(mm[7], m7);
  }
  float4 o0 = make_float4(ms[0]*0.0625f, ms[1]*0.0625f, ms[2]*0.0625f, ms[3]*0.0625f);
  float4 o1 = make_float4(ms[4]*0.0625f, ms[5]*0.0625f, ms[6]*0.0625f, ms[7]*0.0625f);
  *(float4*)&agg[(size_t)i*64 + tq*8]      = o0;
  *(float4*)&agg[(size_t)i*64 + tq*8 + 4]  = o1;
  *(float4*)&agg[(size_t)i*64 + 32 + tq*8]     = make_float4(mm[0], mm[1], mm[2], mm[3]);
  *(float4*)&agg[(size_t)i*64 + 32 + tq*8 + 4] = make_float4(mm[4], mm[5], mm[6], mm[7]);
}

// ---------------- Kernel 4a: pack/transpose weights ----------------
__global__ __launch_bounds__(256) void k4a_wt(
    const float* __restrict__ W1, const float* __restrict__ W2, float* __restrict__ wT) {
  int idx = blockIdx.x*256 + threadIdx.x;
  if (idx >= 192*COUT) return;
  int k = idx >> 7, c = idx & 127;
  float v = (k < 128) ? W1[(size_t)c*128 + k] : W2[(size_t)c*64 + (k - 128)];
  wT[(size_t)k*COUT + c] = v;
}

// ---------------- Kernel 4: out = x@W1^T + agg@W2^T + b2 (32x128 tile, 4x4/thread) ----------
__global__ __launch_bounds__(256) void k4_out2(
    const float* __restrict__ x, const float* __restrict__ agg,
    const float* __restrict__ wT, const float* __restrict__ b2,
    float* __restrict__ out) {
  __shared__ float xa[32*192];
  const int t = threadIdx.x;
  const int row0 = blockIdx.x * 32;
#pragma unroll
  for (int g = 0; g < 4; ++g) {
    int fi = g*256 + t;
    int r = fi >> 5, c4 = fi & 31;
    *(float4*)&xa[r*192 + c4*4] = *(const float4*)&x[(size_t)(row0+r)*CIN + c4*4];
  }
#pragma unroll
  for (int g = 0; g < 2; ++g) {
    int fi = g*256 + t;
    int r = fi >> 4, c4 = fi & 15;
    *(float4*)&xa[r*192 + 128 + c4*4] = *(const float4*)&agg[(size_t)(row0+r)*64 + c4*4];
  }
  __syncthreads();
  const int c4 = t & 31;
  const int rg = t >> 5;
  float acc[4][4];
#pragma unroll
  for (int r = 0; r < 4; ++r) { acc[r][0]=0.f; acc[r][1]=0.f; acc[r][2]=0.f; acc[r][3]=0.f; }
  for (int k = 0; k < 192; k += 4) {
    float4 w0 = *(const float4*)&wT[(size_t)(k+0)*COUT + c4*4];
    float4 w1 = *(const float4*)&wT[(size_t)(k+1)*COUT + c4*4];
    float4 w2 = *(const float4*)&wT[(size_t)(k+2)*COUT + c4*4];
    float4 w3 = *(const float4*)&wT[(size_t)(k+3)*COUT + c4*4];
#pragma unroll
    for (int r = 0; r < 4; ++r) {
      float4 xv = *(const float4*)&xa[(rg*4 + r)*192 + k];
      acc[r][0] = fmaf(xv.x, w0.x, fmaf(xv.y, w1.x, fmaf(xv.z, w2.x, fmaf(xv.w, w3.x, acc[r][0]))));
      acc[r][1] = fmaf(xv.x, w0.y, fmaf(xv.y, w1.y, fmaf(xv.z, w2.y, fmaf(xv.w, w3.y, acc[r][1]))));
      acc[r][2] = fmaf(xv.x, w0.z, fmaf(xv.y, w1.z, fmaf(xv.z, w2.z, fmaf(xv.w, w3.z, acc[r][2]))));
      acc[r][3] = fmaf(xv.x, w0.w, fmaf(xv.y, w1.w, fmaf(xv.z, w2.w, fmaf(xv.w, w3.w, acc[r][3]))));
    }
  }
  float4 bias = *(const float4*)&b2[c4*4];
#pragma unroll
  for (int r = 0; r < 4; ++r) {
    float4 o = make_float4(acc[r][0]+bias.x, acc[r][1]+bias.y, acc[r][2]+bias.z, acc[r][3]+bias.w);
    *(float4*)&out[(size_t)(row0 + rg*4 + r)*COUT + c4*4] = o;
  }
}

extern "C" void kernel_launch(void* const* d_in, const int* in_sizes, int n_in,
                              void* d_out, int out_size, void* d_ws, size_t ws_size,
                              hipStream_t stream) {
  const float* x  = (const float*)d_in[0];
  const float* Ws = (const float*)d_in[1];
  const float* bs = (const float*)d_in[2];
  const float* Wh = (const float*)d_in[3];
  const float* bh = (const float*)d_in[4];
  const float* W1 = (const float*)d_in[5];
  const float* W2 = (const float*)d_in[6];
  const float* b2 = (const float*)d_in[7];
  float* out = (float*)d_out;

  char* ws = (char*)d_ws;
  float4* s4 = (float4*)(ws + WS_S4);
  float*  h  = (float*) (ws + WS_H);

  k1_proj<<<NPTS/64, 256, 0, stream>>>(x, Ws, bs, Wh, bh, s4, h);

  if (ws_size >= (size_t)WS_NEED_M) {
    float* t2  = (float*)(ws + WS_T2);
    float* agg = (float*)(ws + WS_AGG_M);
    float* wT  = (float*)(ws + WS_WT_M);
    uint*  mw  = (uint*) (ws + WS_MASK);
    k2t_thresh<<<NPTS/16, 256, 0, stream>>>(s4, t2);
    k2b_mask<<<1024, 256, 0, stream>>>(s4, t2, mw);
    k3_sel4<<<NPTS/QB3, 256, 0, stream>>>(s4, (const float4*)h, t2, mw, agg);
    k4a_wt<<<(192*COUT + 255)/256, 256, 0, stream>>>(W1, W2, wT);
    k4_out2<<<NPTS/32, 256, 0, stream>>>(x, agg, wT, b2, out);
  } else {
    unsigned short* cj = (unsigned short*)(ws + WS_CJ_F);
    float* agg = (float*)(ws + WS_AGG_F);
    float* wT  = (float*)(ws + WS_WT_F);
    k2_knn_fb<<<512, 256, 0, stream>>>(s4, cj);
    k3_merge_fb<<<NPTS/64, 256, 0, stream>>>(s4, (const float4*)h, cj, agg);
    k4a_wt<<<(192*COUT + 255)/256, 256, 0, stream>>>(W1, W2, wT);
    k4_out2<<<NPTS/32, 256, 0, stream>>>(x, agg, wT, b2, out);
  }
}